// Round 3
// baseline (1249.873 us; speedup 1.0000x reference)
//
#include <hip/hip_runtime.h>
#include <math.h>
#include <stdio.h>

#define NN 131072
#define EE 2097152
#define GG 1024

// ---------------- setup kernels ----------------

__global__ __launch_bounds__(256) void k_init(float* deg, int* cnt) {
    int n = blockIdx.x * 256 + threadIdx.x;
    deg[n] = 1.0f;   // self-loop weight
    cnt[n] = 0;
}

// accumulate weighted degree AND in-degree count per destination
__global__ __launch_bounds__(256) void k_deg(const int* __restrict__ ei,
                                             const float* __restrict__ w,
                                             float* __restrict__ deg,
                                             int* __restrict__ cnt) {
    int e = blockIdx.x * 256 + threadIdx.x;
    int c = ei[EE + e];
    atomicAdd(&deg[c], w[e]);
    atomicAdd(&cnt[c], 1);
}

// deg -> dis (in place), and s = dis^2 * x  (self-loop part of layer-1 scalar agg)
__global__ __launch_bounds__(256) void k_dis(const float* __restrict__ x,
                                             float* __restrict__ deg_dis,
                                             float* __restrict__ s) {
    int n = blockIdx.x * 256 + threadIdx.x;
    float d = deg_dis[n];
    float di = 1.0f / sqrtf(d);   // deg >= 1 always (self-loop)
    deg_dis[n] = di;
    s[n] = di * di * x[n];
}

// exclusive prefix scan of cnt -> offs[NN+1]; cur = copy of offs
// single block, 1024 threads x 128 nodes each
__global__ __launch_bounds__(1024) void k_scan(const int* __restrict__ cnt,
                                               int* __restrict__ offs,
                                               int* __restrict__ cur) {
    __shared__ int part[1024];
    int t = threadIdx.x;
    int base = t * 128;
    int sum = 0;
    for (int i = 0; i < 128; ++i) sum += cnt[base + i];
    part[t] = sum;
    __syncthreads();
    for (int off = 1; off < 1024; off <<= 1) {
        int v = (t >= off) ? part[t - off] : 0;
        __syncthreads();
        part[t] += v;
        __syncthreads();
    }
    int run = (t == 0) ? 0 : part[t - 1];
    for (int i = 0; i < 128; ++i) {
        int n = base + i;
        offs[n] = run;
        cur[n] = run;
        run += cnt[n];
    }
    if (t == 1023) offs[NN] = run;   // == EE
}

// CSR scatter: bucket edges by destination; precompute norm; fuse layer-1 scalar agg
__global__ __launch_bounds__(256) void k_scatter(const int* __restrict__ ei,
                                                 const float* __restrict__ w,
                                                 const float* __restrict__ x,
                                                 const float* __restrict__ dis,
                                                 int* __restrict__ cur,
                                                 float* __restrict__ s,
                                                 uint2* __restrict__ pairs) {
    int e = blockIdx.x * 256 + threadIdx.x;
    int r = ei[e];
    int c = ei[EE + e];
    float nrm = dis[r] * w[e] * dis[c];
    int pos = atomicAdd(&cur[c], 1);
    uint2 p;
    p.x = (unsigned)r;
    p.y = __float_as_uint(nrm);
    pairs[pos] = p;
    atomicAdd(&s[c], nrm * x[r]);
}

// h1[n][j] = relu(s[n]*W1[j] + b1[j])  -> A
__global__ __launch_bounds__(256) void k_h1(const float* __restrict__ s,
                                            const float* __restrict__ W1,
                                            const float* __restrict__ b1,
                                            float* __restrict__ A) {
    int t = blockIdx.x * 256 + threadIdx.x;   // t < NN*32
    int n = t >> 5;
    int jj = (t & 31) * 4;
    float sv = s[n];
    float4 wv = *(const float4*)(W1 + jj);
    float4 bv = *(const float4*)(b1 + jj);
    float4 o;
    o.x = fmaxf(fmaf(sv, wv.x, bv.x), 0.f);
    o.y = fmaxf(fmaf(sv, wv.y, bv.y), 0.f);
    o.z = fmaxf(fmaf(sv, wv.z, bv.z), 0.f);
    o.w = fmaxf(fmaf(sv, wv.w, bv.w), 0.f);
    *(float4*)(A + (size_t)n * 128 + jj) = o;
}

// pull-based propagation at width 128: one wave per node, float2 per lane.
// EPI=1: out = relu(acc + bias)   (layer-3 epilogue)
template <int EPI>
__global__ __launch_bounds__(256) void k_prop(const float* __restrict__ Ain,
                                              float* __restrict__ Bout,
                                              const float* __restrict__ dis,
                                              const int* __restrict__ offs,
                                              const uint2* __restrict__ pairs,
                                              const float* __restrict__ bias) {
    int gtid = blockIdx.x * 256 + threadIdx.x;
    int n = gtid >> 6;          // wave id == node id
    int lane = threadIdx.x & 63;
    const float2* A2 = (const float2*)Ain;
    float dn = dis[n];
    float sn = dn * dn;         // self-loop norm
    float2 av = A2[(size_t)n * 64 + lane];
    float accx = sn * av.x, accy = sn * av.y;
    int k0 = offs[n], k1 = offs[n + 1];
    for (int k = k0; k < k1; ++k) {
        uint2 p = pairs[k];                      // broadcast load (same addr all lanes)
        float nrm = __uint_as_float(p.y);
        float2 rv = A2[(size_t)p.x * 64 + lane]; // 512B coalesced gather
        accx = fmaf(nrm, rv.x, accx);
        accy = fmaf(nrm, rv.y, accy);
    }
    if (EPI) {
        float2 bv = ((const float2*)bias)[lane];
        accx = fmaxf(accx + bv.x, 0.f);
        accy = fmaxf(accy + bv.y, 0.f);
    }
    float2 o; o.x = accx; o.y = accy;
    ((float2*)Bout)[(size_t)n * 64 + lane] = o;
}

// A[N,128] = ( relu(B[N,128] @ W2[128,256] + b2) ) @ W3[256,128]
// 64-node tile per block, 256 threads. Intermediate 64x256 tile lives in LDS
// (aliased with the B staging buffer: 64KB total -> 2 blocks/CU).
__global__ __launch_bounds__(256) void k_gemm23(const float* __restrict__ Bin,
                                                const float* __restrict__ W2,
                                                const float* __restrict__ b2,
                                                const float* __restrict__ W3,
                                                float* __restrict__ A) {
    __shared__ float smem[64 * 256];           // 64 KB; first 32KB doubles as Bt
    float* Bt = smem;                          // [64][128]
    float* Ct = smem;                          // [64][256] (reused after barrier)
    int n0 = blockIdx.x * 64;
    int t = threadIdx.x;
    int jl = t & 63;
    int mg = t >> 6;

    // stage B tile
    {
        const float4* src = (const float4*)(Bin + (size_t)n0 * 128);
        float4* dst = (float4*)Bt;
#pragma unroll
        for (int i = 0; i < 8; ++i) dst[i * 256 + t] = src[i * 256 + t];
    }
    __syncthreads();

    // ---- GEMM2: acc[m][q] = Bt[mg*16+m][:] . W2[:][jl+64q] ----
    float acc[16][4];
#pragma unroll
    for (int m = 0; m < 16; ++m)
#pragma unroll
        for (int q = 0; q < 4; ++q) acc[m][q] = 0.f;

    for (int k = 0; k < 128; k += 4) {
        float wv[4][4];
#pragma unroll
        for (int kk = 0; kk < 4; ++kk)
#pragma unroll
            for (int q = 0; q < 4; ++q)
                wv[kk][q] = W2[(k + kk) * 256 + jl + q * 64];
#pragma unroll
        for (int m = 0; m < 16; ++m) {
            float4 bv = *(const float4*)&Bt[(mg * 16 + m) * 128 + k];  // LDS broadcast
            acc[m][0] = fmaf(bv.x, wv[0][0], acc[m][0]);
            acc[m][1] = fmaf(bv.x, wv[0][1], acc[m][1]);
            acc[m][2] = fmaf(bv.x, wv[0][2], acc[m][2]);
            acc[m][3] = fmaf(bv.x, wv[0][3], acc[m][3]);
            acc[m][0] = fmaf(bv.y, wv[1][0], acc[m][0]);
            acc[m][1] = fmaf(bv.y, wv[1][1], acc[m][1]);
            acc[m][2] = fmaf(bv.y, wv[1][2], acc[m][2]);
            acc[m][3] = fmaf(bv.y, wv[1][3], acc[m][3]);
            acc[m][0] = fmaf(bv.z, wv[2][0], acc[m][0]);
            acc[m][1] = fmaf(bv.z, wv[2][1], acc[m][1]);
            acc[m][2] = fmaf(bv.z, wv[2][2], acc[m][2]);
            acc[m][3] = fmaf(bv.z, wv[2][3], acc[m][3]);
            acc[m][0] = fmaf(bv.w, wv[3][0], acc[m][0]);
            acc[m][1] = fmaf(bv.w, wv[3][1], acc[m][1]);
            acc[m][2] = fmaf(bv.w, wv[3][2], acc[m][2]);
            acc[m][3] = fmaf(bv.w, wv[3][3], acc[m][3]);
        }
    }
    __syncthreads();   // all Bt reads done before Ct overwrite

    // relu(+bias) -> Ct
    {
        float bb0 = b2[jl], bb1 = b2[jl + 64], bb2 = b2[jl + 128], bb3 = b2[jl + 192];
#pragma unroll
        for (int m = 0; m < 16; ++m) {
            float* cp = Ct + (mg * 16 + m) * 256;
            cp[jl]       = fmaxf(acc[m][0] + bb0, 0.f);
            cp[jl + 64]  = fmaxf(acc[m][1] + bb1, 0.f);
            cp[jl + 128] = fmaxf(acc[m][2] + bb2, 0.f);
            cp[jl + 192] = fmaxf(acc[m][3] + bb3, 0.f);
        }
    }
    __syncthreads();

    // ---- GEMM3: out[m][q] = Ct[mg*16+m][:] . W3[:][jl+64q] ----
    float acc2[16][2];
#pragma unroll
    for (int m = 0; m < 16; ++m) { acc2[m][0] = 0.f; acc2[m][1] = 0.f; }

    for (int k = 0; k < 256; k += 4) {
        float wv[4][2];
#pragma unroll
        for (int kk = 0; kk < 4; ++kk) {
            wv[kk][0] = W3[(k + kk) * 128 + jl];
            wv[kk][1] = W3[(k + kk) * 128 + jl + 64];
        }
#pragma unroll
        for (int m = 0; m < 16; ++m) {
            float4 cv = *(const float4*)&Ct[(mg * 16 + m) * 256 + k];
            acc2[m][0] = fmaf(cv.x, wv[0][0], acc2[m][0]);
            acc2[m][1] = fmaf(cv.x, wv[0][1], acc2[m][1]);
            acc2[m][0] = fmaf(cv.y, wv[1][0], acc2[m][0]);
            acc2[m][1] = fmaf(cv.y, wv[1][1], acc2[m][1]);
            acc2[m][0] = fmaf(cv.z, wv[2][0], acc2[m][0]);
            acc2[m][1] = fmaf(cv.z, wv[2][1], acc2[m][1]);
            acc2[m][0] = fmaf(cv.w, wv[3][0], acc2[m][0]);
            acc2[m][1] = fmaf(cv.w, wv[3][1], acc2[m][1]);
        }
    }
#pragma unroll
    for (int m = 0; m < 16; ++m) {
        float* ap = A + (size_t)(n0 + mg * 16 + m) * 128;
        ap[jl]      = acc2[m][0];
        ap[jl + 64] = acc2[m][1];
    }
}

// mean pool per graph; batch is sorted -> binary search the segment
__global__ __launch_bounds__(128) void k_pool(const float* __restrict__ h,
                                              const int* __restrict__ batch,
                                              float* __restrict__ pooled) {
    int g = blockIdx.x;
    int j = threadIdx.x;
    int lo = 0, hi = NN;
    while (lo < hi) { int mid = (lo + hi) >> 1; if (batch[mid] < g) lo = mid + 1; else hi = mid; }
    int s0 = lo;
    lo = s0; hi = NN;
    while (lo < hi) { int mid = (lo + hi) >> 1; if (batch[mid] < g + 1) lo = mid + 1; else hi = mid; }
    int s1 = lo;
    float acc = 0.f;
    for (int n = s0; n < s1; ++n) acc += h[(size_t)n * 128 + j];
    float c = (float)(s1 - s0);
    if (c < 1.f) c = 1.f;
    pooled[g * 128 + j] = acc / c;
}

__global__ __launch_bounds__(128) void k_mlp(const float* __restrict__ pooled,
                                             const float* __restrict__ Wf1,
                                             const float* __restrict__ bf1,
                                             const float* __restrict__ Wf2,
                                             const float* __restrict__ bf2,
                                             float* __restrict__ out) {
    __shared__ float p[128];
    __shared__ float z[32];
    int g = blockIdx.x;
    int t = threadIdx.x;
    p[t] = pooled[g * 128 + t];
    __syncthreads();
    if (t < 32) {
        float a = bf1[t];
        for (int k = 0; k < 128; ++k) a = fmaf(p[k], Wf1[k * 32 + t], a);
        z[t] = fmaxf(a, 0.f);
    }
    __syncthreads();
    if (t < 2) {
        float a = bf2[t];
        for (int j = 0; j < 32; ++j) a = fmaf(z[j], Wf2[j * 2 + t], a);
        out[g * 2 + t] = a;
    }
}

extern "C" void kernel_launch(void* const* d_in, const int* in_sizes, int n_in,
                              void* d_out, int out_size, void* d_ws, size_t ws_size,
                              hipStream_t stream) {
    const float* x   = (const float*)d_in[0];
    const int*   ei  = (const int*)d_in[1];
    const float* w   = (const float*)d_in[2];
    const int*   bat = (const int*)d_in[3];
    const float* W1  = (const float*)d_in[4];
    const float* b1  = (const float*)d_in[5];
    const float* W2  = (const float*)d_in[6];
    const float* b2  = (const float*)d_in[7];
    const float* W3  = (const float*)d_in[8];
    const float* b3  = (const float*)d_in[9];
    const float* Wf1 = (const float*)d_in[10];
    const float* bf1 = (const float*)d_in[11];
    const float* Wf2 = (const float*)d_in[12];
    const float* bf2 = (const float*)d_in[13];
    float* out = (float*)d_out;

    char* ws = (char*)d_ws;
    size_t o = 0;
    auto alloc = [&](size_t bytes) {
        void* p = ws + o;
        o += (bytes + 255) & ~(size_t)255;
        return p;
    };
    float* deg_dis = (float*)alloc((size_t)NN * 4);
    float* s       = (float*)alloc((size_t)NN * 4);
    int*   cnt     = (int*)alloc((size_t)NN * 4);
    int*   offs    = (int*)alloc((size_t)(NN + 1) * 4);
    int*   cur     = (int*)alloc((size_t)NN * 4);
    uint2* pairs   = (uint2*)alloc((size_t)EE * 8);          // 16 MB
    float* A       = (float*)alloc((size_t)NN * 128 * 4);    // 64 MB
    float* B       = (float*)alloc((size_t)NN * 128 * 4);    // 64 MB
    float* pooled  = (float*)alloc((size_t)GG * 128 * 4);

    if (o > ws_size) {
        fprintf(stderr, "[kernel_launch] ws_size=%zu < needed=%zu — aborting launch\n",
                ws_size, o);
        return;
    }

    k_init<<<NN / 256, 256, 0, stream>>>(deg_dis, cnt);
    k_deg<<<EE / 256, 256, 0, stream>>>(ei, w, deg_dis, cnt);
    k_dis<<<NN / 256, 256, 0, stream>>>(x, deg_dis, s);
    k_scan<<<1, 1024, 0, stream>>>(cnt, offs, cur);
    k_scatter<<<EE / 256, 256, 0, stream>>>(ei, w, x, deg_dis, cur, s, pairs);
    k_h1<<<(NN * 32) / 256, 256, 0, stream>>>(s, W1, b1, A);
    k_prop<0><<<NN / 4, 256, 0, stream>>>(A, B, deg_dis, offs, pairs, nullptr);
    k_gemm23<<<NN / 64, 256, 0, stream>>>(B, W2, b2, W3, A);
    k_prop<1><<<NN / 4, 256, 0, stream>>>(A, B, deg_dis, offs, pairs, b3);
    k_pool<<<GG, 128, 0, stream>>>(B, bat, pooled);
    k_mlp<<<GG, 128, 0, stream>>>(pooled, Wf1, bf1, Wf2, bf2, out);
}

// Round 5
// 1222.255 us; speedup vs baseline: 1.0226x; 1.0226x over previous
//
#include <hip/hip_runtime.h>
#include <math.h>
#include <stdio.h>

#define NN 131072
#define EE 2097152
#define GG 1024

typedef _Float16 half_t;
typedef _Float16 f16x2 __attribute__((ext_vector_type(2)));
typedef _Float16 f16x4 __attribute__((ext_vector_type(4)));
typedef float f32x4 __attribute__((ext_vector_type(4)));

// ---------------- setup kernels ----------------

__global__ __launch_bounds__(256) void k_init(float* deg, int* cnt) {
    int n = blockIdx.x * 256 + threadIdx.x;
    deg[n] = 1.0f;   // self-loop weight
    cnt[n] = 0;
}

__global__ __launch_bounds__(256) void k_deg(const int* __restrict__ ei,
                                             const float* __restrict__ w,
                                             float* __restrict__ deg,
                                             int* __restrict__ cnt) {
    int e = blockIdx.x * 256 + threadIdx.x;
    int c = ei[EE + e];
    atomicAdd(&deg[c], w[e]);
    atomicAdd(&cnt[c], 1);
}

__global__ __launch_bounds__(256) void k_dis(const float* __restrict__ x,
                                             float* __restrict__ deg_dis,
                                             float* __restrict__ s) {
    int n = blockIdx.x * 256 + threadIdx.x;
    float d = deg_dis[n];
    float di = 1.0f / sqrtf(d);
    deg_dis[n] = di;
    s[n] = di * di * x[n];
}

// exclusive prefix scan of cnt -> offs[NN+1]; cur = copy
__global__ __launch_bounds__(1024) void k_scan(const int* __restrict__ cnt,
                                               int* __restrict__ offs,
                                               int* __restrict__ cur) {
    __shared__ int part[1024];
    int t = threadIdx.x;
    int base = t * 128;
    int sum = 0;
    for (int i = 0; i < 128; ++i) sum += cnt[base + i];
    part[t] = sum;
    __syncthreads();
    for (int off = 1; off < 1024; off <<= 1) {
        int v = (t >= off) ? part[t - off] : 0;
        __syncthreads();
        part[t] += v;
        __syncthreads();
    }
    int run = (t == 0) ? 0 : part[t - 1];
    for (int i = 0; i < 128; ++i) {
        int n = base + i;
        offs[n] = run;
        cur[n] = run;
        run += cnt[n];
    }
    if (t == 1023) offs[NN] = run;
}

__global__ __launch_bounds__(256) void k_scatter(const int* __restrict__ ei,
                                                 const float* __restrict__ w,
                                                 const float* __restrict__ x,
                                                 const float* __restrict__ dis,
                                                 int* __restrict__ cur,
                                                 float* __restrict__ s,
                                                 uint2* __restrict__ pairs) {
    int e = blockIdx.x * 256 + threadIdx.x;
    int r = ei[e];
    int c = ei[EE + e];
    float nrm = dis[r] * w[e] * dis[c];
    int pos = atomicAdd(&cur[c], 1);
    uint2 p;
    p.x = (unsigned)r;
    p.y = __float_as_uint(nrm);
    pairs[pos] = p;
    atomicAdd(&s[c], nrm * x[r]);
}

// weight transpose + fp16 convert (tiny, once per call)
__global__ __launch_bounds__(256) void k_w2t(const float* __restrict__ W2, half_t* __restrict__ W2t) {
    int t = blockIdx.x * 256 + threadIdx.x;   // 32768 = 256*128
    int n = t >> 7;        // 0..255
    int k = t & 127;       // 0..127
    W2t[t] = (half_t)W2[k * 256 + n];
}
__global__ __launch_bounds__(256) void k_w3t(const float* __restrict__ W3, half_t* __restrict__ W3t) {
    int t = blockIdx.x * 256 + threadIdx.x;   // 32768 = 128*256
    int n = t >> 8;        // 0..127
    int k = t & 255;       // 0..255
    W3t[t] = (half_t)W3[k * 128 + n];
}

// h1[n][j] = relu(s[n]*W1[j] + b1[j])  -> Ah (fp16)
__global__ __launch_bounds__(256) void k_h1(const float* __restrict__ s,
                                            const float* __restrict__ W1,
                                            const float* __restrict__ b1,
                                            half_t* __restrict__ Ah) {
    int t = blockIdx.x * 256 + threadIdx.x;
    int n = t >> 5;
    int jj = (t & 31) * 4;
    float sv = s[n];
    float4 wv = *(const float4*)(W1 + jj);
    float4 bv = *(const float4*)(b1 + jj);
    f16x4 o;
    o.x = (half_t)fmaxf(fmaf(sv, wv.x, bv.x), 0.f);
    o.y = (half_t)fmaxf(fmaf(sv, wv.y, bv.y), 0.f);
    o.z = (half_t)fmaxf(fmaf(sv, wv.z, bv.z), 0.f);
    o.w = (half_t)fmaxf(fmaf(sv, wv.w, bv.w), 0.f);
    *(f16x4*)(Ah + (size_t)n * 128 + jj) = o;
}

// pull-propagation, fp16 features, fp32 accumulate. One wave per node, f16x2/lane.
template <int EPI>
__global__ __launch_bounds__(256) void k_prop(const half_t* __restrict__ Ain,
                                              half_t* __restrict__ Bout,
                                              const float* __restrict__ dis,
                                              const int* __restrict__ offs,
                                              const uint2* __restrict__ pairs,
                                              const float* __restrict__ bias) {
    int gtid = blockIdx.x * 256 + threadIdx.x;
    int n = gtid >> 6;
    int lane = threadIdx.x & 63;
    const f16x2* A2 = (const f16x2*)Ain;
    float dn = dis[n];
    float sn = dn * dn;
    f16x2 av = A2[(size_t)n * 64 + lane];
    float accx = sn * (float)av.x, accy = sn * (float)av.y;
    int k0 = offs[n], k1 = offs[n + 1];
    for (int k = k0; k < k1; ++k) {
        uint2 p = pairs[k];                       // wave-uniform 8B load
        float nrm = __uint_as_float(p.y);
        f16x2 rv = A2[(size_t)p.x * 64 + lane];   // 256B coalesced row gather
        accx = fmaf(nrm, (float)rv.x, accx);
        accy = fmaf(nrm, (float)rv.y, accy);
    }
    if (EPI) {
        float2 bv = ((const float2*)bias)[lane];
        accx = fmaxf(accx + bv.x, 0.f);
        accy = fmaxf(accy + bv.y, 0.f);
    }
    f16x2 o;
    o.x = (half_t)accx;
    o.y = (half_t)accy;
    ((f16x2*)Bout)[(size_t)n * 64 + lane] = o;
}

// Ah[N,128] = ( relu(Bh[N,128] @ W2 + b2) ) @ W3   -- MFMA f16, fp32 accum.
// Block: 64 nodes, 4 waves; wave w owns rows [w*16, w*16+16).
// v_mfma_f32_16x16x16_f16 layouts (classic CDNA): A: i=lane%16, k=4*(lane/16)+slot;
// B: j=lane%16, k=4*(lane/16)+slot; D: col=lane&15, row=(lane>>4)*4+reg.
__global__ __launch_bounds__(256) void k_gemm23(const half_t* __restrict__ Bh,
                                                const half_t* __restrict__ W2t,  // [256][128] f16
                                                const float* __restrict__ b2,
                                                const half_t* __restrict__ W3t,  // [128][256] f16
                                                half_t* __restrict__ Ah) {
    __shared__ __align__(16) char CtB[64 * 512];   // Ct[64][256] f16, XOR-swizzled rows
    int n0 = blockIdx.x * 64;
    int t = threadIdx.x;
    int wv = t >> 6;
    int lane = t & 63;
    int lr = lane & 15;    // A-row / B-col / D-col within 16-tile
    int lc = lane >> 4;    // k-subgroup 0..3

    // ---- GEMM2: [64x128] @ [128x256] ----
    // A-frags: 8 k-steps of 16; lane reads 4 contiguous halves (8B)
    f16x4 a2[8];
    {
        const char* arow = (const char*)(Bh + (size_t)(n0 + wv * 16 + lr) * 128) + lc * 8;
#pragma unroll
        for (int ks = 0; ks < 8; ++ks)
            a2[ks] = *(const f16x4*)(arow + ks * 32);
    }
#pragma unroll 4
    for (int nt = 0; nt < 16; ++nt) {
        f32x4 acc = {0.f, 0.f, 0.f, 0.f};
        const char* wcol = (const char*)(W2t + (size_t)(nt * 16 + lr) * 128) + lc * 8;
#pragma unroll
        for (int ks = 0; ks < 8; ++ks) {
            f16x4 b = *(const f16x4*)(wcol + ks * 32);
            acc = __builtin_amdgcn_mfma_f32_16x16x16f16(a2[ks], b, acc, 0, 0, 0);
        }
        float bias = b2[nt * 16 + lr];
#pragma unroll
        for (int r = 0; r < 4; ++r) {
            int row = wv * 16 + lc * 4 + r;
            int coff = (nt * 16 + lr) * 2;
            float v = fmaxf(acc[r] + bias, 0.f);
            *(half_t*)(CtB + row * 512 + (coff ^ ((row & 7) << 4))) = (half_t)v;
        }
    }
    __syncthreads();

    // ---- GEMM3: [64x256] @ [256x128] ----
    f16x4 a3[16];
    {
        int row = wv * 16 + lr;
        const char* rbase = CtB + row * 512;
        int sw = (row & 7) << 4;
#pragma unroll
        for (int ks = 0; ks < 16; ++ks)
            a3[ks] = *(const f16x4*)(rbase + ((ks * 32 + lc * 8) ^ sw));
    }
#pragma unroll 2
    for (int nt = 0; nt < 8; ++nt) {
        f32x4 acc = {0.f, 0.f, 0.f, 0.f};
        const char* wcol = (const char*)(W3t + (size_t)(nt * 16 + lr) * 256) + lc * 8;
#pragma unroll
        for (int ks = 0; ks < 16; ++ks) {
            f16x4 b = *(const f16x4*)(wcol + ks * 32);
            acc = __builtin_amdgcn_mfma_f32_16x16x16f16(a3[ks], b, acc, 0, 0, 0);
        }
#pragma unroll
        for (int r = 0; r < 4; ++r) {
            int row = n0 + wv * 16 + lc * 4 + r;
            Ah[(size_t)row * 128 + nt * 16 + lr] = (half_t)acc[r];
        }
    }
}

// mean pool per graph; batch sorted -> binary search segment. Bh fp16.
__global__ __launch_bounds__(128) void k_pool(const half_t* __restrict__ h,
                                              const int* __restrict__ batch,
                                              float* __restrict__ pooled) {
    int g = blockIdx.x;
    int j = threadIdx.x;
    int lo = 0, hi = NN;
    while (lo < hi) { int mid = (lo + hi) >> 1; if (batch[mid] < g) lo = mid + 1; else hi = mid; }
    int s0 = lo;
    lo = s0; hi = NN;
    while (lo < hi) { int mid = (lo + hi) >> 1; if (batch[mid] < g + 1) lo = mid + 1; else hi = mid; }
    int s1 = lo;
    float acc = 0.f;
    for (int n = s0; n < s1; ++n) acc += (float)h[(size_t)n * 128 + j];
    float c = (float)(s1 - s0);
    if (c < 1.f) c = 1.f;
    pooled[g * 128 + j] = acc / c;
}

__global__ __launch_bounds__(128) void k_mlp(const float* __restrict__ pooled,
                                             const float* __restrict__ Wf1,
                                             const float* __restrict__ bf1,
                                             const float* __restrict__ Wf2,
                                             const float* __restrict__ bf2,
                                             float* __restrict__ out) {
    __shared__ float p[128];
    __shared__ float z[32];
    int g = blockIdx.x;
    int t = threadIdx.x;
    p[t] = pooled[g * 128 + t];
    __syncthreads();
    if (t < 32) {
        float a = bf1[t];
        for (int k = 0; k < 128; ++k) a = fmaf(p[k], Wf1[k * 32 + t], a);
        z[t] = fmaxf(a, 0.f);
    }
    __syncthreads();
    if (t < 2) {
        float a = bf2[t];
        for (int j = 0; j < 32; ++j) a = fmaf(z[j], Wf2[j * 2 + t], a);
        out[g * 2 + t] = a;
    }
}

extern "C" void kernel_launch(void* const* d_in, const int* in_sizes, int n_in,
                              void* d_out, int out_size, void* d_ws, size_t ws_size,
                              hipStream_t stream) {
    const float* x   = (const float*)d_in[0];
    const int*   ei  = (const int*)d_in[1];
    const float* w   = (const float*)d_in[2];
    const int*   bat = (const int*)d_in[3];
    const float* W1  = (const float*)d_in[4];
    const float* b1  = (const float*)d_in[5];
    const float* W2  = (const float*)d_in[6];
    const float* b2  = (const float*)d_in[7];
    const float* W3  = (const float*)d_in[8];
    const float* b3  = (const float*)d_in[9];
    const float* Wf1 = (const float*)d_in[10];
    const float* bf1 = (const float*)d_in[11];
    const float* Wf2 = (const float*)d_in[12];
    const float* bf2 = (const float*)d_in[13];
    float* out = (float*)d_out;

    char* ws = (char*)d_ws;
    size_t o = 0;
    auto alloc = [&](size_t bytes) {
        void* p = ws + o;
        o += (bytes + 255) & ~(size_t)255;
        return p;
    };
    float*  deg_dis = (float*)alloc((size_t)NN * 4);
    float*  s       = (float*)alloc((size_t)NN * 4);
    int*    cnt     = (int*)alloc((size_t)NN * 4);
    int*    offs    = (int*)alloc((size_t)(NN + 1) * 4);
    int*    cur     = (int*)alloc((size_t)NN * 4);
    uint2*  pairs   = (uint2*)alloc((size_t)EE * 8);            // 16 MB
    half_t* Ah      = (half_t*)alloc((size_t)NN * 128 * 2);     // 32 MB
    half_t* Bh      = (half_t*)alloc((size_t)NN * 128 * 2);     // 32 MB
    half_t* W2t     = (half_t*)alloc((size_t)256 * 128 * 2);
    half_t* W3t     = (half_t*)alloc((size_t)128 * 256 * 2);
    float*  pooled  = (float*)alloc((size_t)GG * 128 * 4);

    if (o > ws_size) {
        fprintf(stderr, "[kernel_launch] ws_size=%zu < needed=%zu — aborting launch\n",
                ws_size, o);
        return;
    }

    k_init<<<NN / 256, 256, 0, stream>>>(deg_dis, cnt);
    k_deg<<<EE / 256, 256, 0, stream>>>(ei, w, deg_dis, cnt);
    k_dis<<<NN / 256, 256, 0, stream>>>(x, deg_dis, s);
    k_scan<<<1, 1024, 0, stream>>>(cnt, offs, cur);
    k_scatter<<<EE / 256, 256, 0, stream>>>(ei, w, x, deg_dis, cur, s, pairs);
    k_w2t<<<128, 256, 0, stream>>>(W2, W2t);
    k_w3t<<<128, 256, 0, stream>>>(W3, W3t);
    k_h1<<<(NN * 32) / 256, 256, 0, stream>>>(s, W1, b1, Ah);
    k_prop<0><<<NN / 4, 256, 0, stream>>>(Ah, Bh, deg_dis, offs, pairs, nullptr);
    k_gemm23<<<NN / 64, 256, 0, stream>>>(Bh, W2t, b2, W3t, Ah);
    k_prop<1><<<NN / 4, 256, 0, stream>>>(Ah, Bh, deg_dis, offs, pairs, b3);
    k_pool<<<GG, 128, 0, stream>>>(Bh, bat, pooled);
    k_mlp<<<GG, 128, 0, stream>>>(pooled, Wf1, bf1, Wf2, bf2, out);
}

// Round 6
// 756.514 us; speedup vs baseline: 1.6521x; 1.6156x over previous
//
#include <hip/hip_runtime.h>
#include <math.h>
#include <stdio.h>

#define NN 131072
#define EE 2097152
#define GG 1024

typedef _Float16 half_t;
typedef _Float16 f16x2 __attribute__((ext_vector_type(2)));
typedef _Float16 f16x4 __attribute__((ext_vector_type(4)));
typedef float f32x4 __attribute__((ext_vector_type(4)));

// ---------------- graph build (int atomics only) ----------------

__global__ __launch_bounds__(256) void k_init(int* cnt) {
    cnt[blockIdx.x * 256 + threadIdx.x] = 0;
}

__global__ __launch_bounds__(256) void k_cnt(const int* __restrict__ ei,
                                             int* __restrict__ cnt) {
    int e = blockIdx.x * 256 + threadIdx.x;
    atomicAdd(&cnt[ei[EE + e]], 1);
}

// exclusive prefix scan of cnt -> offs[NN+1]; cur = copy
__global__ __launch_bounds__(1024) void k_scan(const int* __restrict__ cnt,
                                               int* __restrict__ offs,
                                               int* __restrict__ cur) {
    __shared__ int part[1024];
    int t = threadIdx.x;
    int base = t * 128;
    int sum = 0;
    for (int i = 0; i < 128; ++i) sum += cnt[base + i];
    part[t] = sum;
    __syncthreads();
    for (int off = 1; off < 1024; off <<= 1) {
        int v = (t >= off) ? part[t - off] : 0;
        __syncthreads();
        part[t] += v;
        __syncthreads();
    }
    int run = (t == 0) ? 0 : part[t - 1];
    for (int i = 0; i < 128; ++i) {
        int n = base + i;
        offs[n] = run;
        cur[n] = run;
        run += cnt[n];
    }
    if (t == 1023) offs[NN] = run;
}

// bucket edges by destination: pairs[pos] = (src, raw edge weight)
__global__ __launch_bounds__(256) void k_scatter(const int* __restrict__ ei,
                                                 const float* __restrict__ w,
                                                 int* __restrict__ cur,
                                                 uint2* __restrict__ pairs) {
    int e = blockIdx.x * 256 + threadIdx.x;
    int r = ei[e];
    int c = ei[EE + e];
    int pos = atomicAdd(&cur[c], 1);
    uint2 p;
    p.x = (unsigned)r;
    p.y = __float_as_uint(w[e]);
    pairs[pos] = p;
}

// thread per node: deg = 1 + sum(w over segment); xd[n] = (x[n], rsqrt(deg))
__global__ __launch_bounds__(256) void k_degdis(const float* __restrict__ x,
                                                const int* __restrict__ offs,
                                                const uint2* __restrict__ pairs,
                                                float2* __restrict__ xd) {
    int n = blockIdx.x * 256 + threadIdx.x;
    int k0 = offs[n], k1 = offs[n + 1];
    float deg = 1.0f;   // self-loop
    for (int k = k0; k < k1; ++k) deg += __uint_as_float(pairs[k].y);
    float2 v;
    v.x = x[n];
    v.y = rsqrtf(deg);
    xd[n] = v;
}

// wave per node: compute norms (writeback to pairs), reduce s, emit h1 row.
// s = dis_n^2*x_n + sum nrm*x_r ;  h1[n][j] = relu(s*W1[j]+b1[j]) (fp16)
__global__ __launch_bounds__(256) void k_h1f(const float2* __restrict__ xd,
                                             const int* __restrict__ offs,
                                             uint2* __restrict__ pairs,
                                             const float* __restrict__ W1,
                                             const float* __restrict__ b1,
                                             half_t* __restrict__ Ah) {
    int n = (blockIdx.x * 256 + threadIdx.x) >> 6;
    int lane = threadIdx.x & 63;
    float2 xdn = xd[n];
    float dn = xdn.y;
    int k0 = offs[n], k1 = offs[n + 1];
    float s = 0.f;
    for (int kb = k0; kb < k1; kb += 64) {
        int k = kb + lane;
        if (k < k1) {
            uint2 p = pairs[k];
            float2 xr = xd[p.x];                    // random 8B gather
            float nrm = dn * __uint_as_float(p.y) * xr.y;
            pairs[k].y = __float_as_uint(nrm);      // writeback norm
            s = fmaf(nrm, xr.x, s);
        }
    }
#pragma unroll
    for (int off = 32; off > 0; off >>= 1) s += __shfl_xor(s, off);
    s = fmaf(dn * dn, xdn.x, s);
    float2 wv = ((const float2*)W1)[lane];
    float2 bv = ((const float2*)b1)[lane];
    f16x2 o;
    o.x = (half_t)fmaxf(fmaf(s, wv.x, bv.x), 0.f);
    o.y = (half_t)fmaxf(fmaf(s, wv.y, bv.y), 0.f);
    ((f16x2*)Ah)[(size_t)n * 64 + lane] = o;
}

// pull-propagation, fp16 features, fp32 accum, 4-way unrolled gathers.
template <int EPI>
__global__ __launch_bounds__(256) void k_prop(const half_t* __restrict__ Ain,
                                              half_t* __restrict__ Bout,
                                              const float2* __restrict__ xd,
                                              const int* __restrict__ offs,
                                              const uint2* __restrict__ pairs,
                                              const float* __restrict__ bias) {
    int n = (blockIdx.x * 256 + threadIdx.x) >> 6;
    int lane = threadIdx.x & 63;
    const f16x2* A2 = (const f16x2*)Ain;
    float dn = xd[n].y;
    float sn = dn * dn;
    f16x2 av = A2[(size_t)n * 64 + lane];
    float ax0 = sn * (float)av.x, ay0 = sn * (float)av.y;
    float ax1 = 0.f, ay1 = 0.f, ax2 = 0.f, ay2 = 0.f, ax3 = 0.f, ay3 = 0.f;
    int k0 = offs[n], k1 = offs[n + 1];
    int k = k0;
    for (; k + 4 <= k1; k += 4) {
        uint2 p0 = pairs[k], p1 = pairs[k + 1], p2 = pairs[k + 2], p3 = pairs[k + 3];
        f16x2 r0 = A2[(size_t)p0.x * 64 + lane];
        f16x2 r1 = A2[(size_t)p1.x * 64 + lane];
        f16x2 r2 = A2[(size_t)p2.x * 64 + lane];
        f16x2 r3 = A2[(size_t)p3.x * 64 + lane];
        ax0 = fmaf(__uint_as_float(p0.y), (float)r0.x, ax0);
        ay0 = fmaf(__uint_as_float(p0.y), (float)r0.y, ay0);
        ax1 = fmaf(__uint_as_float(p1.y), (float)r1.x, ax1);
        ay1 = fmaf(__uint_as_float(p1.y), (float)r1.y, ay1);
        ax2 = fmaf(__uint_as_float(p2.y), (float)r2.x, ax2);
        ay2 = fmaf(__uint_as_float(p2.y), (float)r2.y, ay2);
        ax3 = fmaf(__uint_as_float(p3.y), (float)r3.x, ax3);
        ay3 = fmaf(__uint_as_float(p3.y), (float)r3.y, ay3);
    }
    for (; k < k1; ++k) {
        uint2 p = pairs[k];
        f16x2 rv = A2[(size_t)p.x * 64 + lane];
        ax0 = fmaf(__uint_as_float(p.y), (float)rv.x, ax0);
        ay0 = fmaf(__uint_as_float(p.y), (float)rv.y, ay0);
    }
    float accx = (ax0 + ax1) + (ax2 + ax3);
    float accy = (ay0 + ay1) + (ay2 + ay3);
    if (EPI) {
        float2 bv = ((const float2*)bias)[lane];
        accx = fmaxf(accx + bv.x, 0.f);
        accy = fmaxf(accy + bv.y, 0.f);
    }
    f16x2 o;
    o.x = (half_t)accx;
    o.y = (half_t)accy;
    ((f16x2*)Bout)[(size_t)n * 64 + lane] = o;
}

// ---- weight packing: fragment-major so each B-frag load is 512B/wave ----
// W2p[((nt*8+ks)*64+lane)*4+slot] = W2[k][col], col=nt*16+(lane&15), k=ks*16+(lane>>4)*4+slot
__global__ __launch_bounds__(256) void k_w2p(const float* __restrict__ W2, half_t* __restrict__ W2p) {
    int t = blockIdx.x * 256 + threadIdx.x;       // 32768
    int slot = t & 3, lane = (t >> 2) & 63, ks = (t >> 8) & 7, nt = t >> 11;
    int col = nt * 16 + (lane & 15);
    int k = ks * 16 + (lane >> 4) * 4 + slot;
    W2p[t] = (half_t)W2[k * 256 + col];
}
__global__ __launch_bounds__(256) void k_w3p(const float* __restrict__ W3, half_t* __restrict__ W3p) {
    int t = blockIdx.x * 256 + threadIdx.x;       // 32768
    int slot = t & 3, lane = (t >> 2) & 63, ks = (t >> 8) & 15, nt = t >> 12;
    int col = nt * 16 + (lane & 15);
    int k = ks * 16 + (lane >> 4) * 4 + slot;
    W3p[t] = (half_t)W3[k * 128 + col];
}

// Ah[N,128] = ( relu(Bh[N,128] @ W2 + b2) ) @ W3 -- MFMA f16, k-outer, 16 indep acc.
// Layout (HW-verified R5): A: i=lane%16, k=4*(lane/16)+slot; B same; D: col=lane&15,
// row=(lane>>4)*4+reg.
__global__ __launch_bounds__(256) void k_gemm23(const half_t* __restrict__ Bh,
                                                const half_t* __restrict__ W2p,
                                                const float* __restrict__ b2,
                                                const half_t* __restrict__ W3p,
                                                half_t* __restrict__ Ah) {
    __shared__ __align__(16) char CtB[64 * 512];   // Ct[64][256] f16, XOR-swizzled rows
    int n0 = blockIdx.x * 64;
    int t = threadIdx.x;
    int wv = t >> 6;
    int lane = t & 63;
    int lr = lane & 15;
    int lc = lane >> 4;

    // ---- GEMM2: [64x128] @ [128x256], wave owns 16 rows x all 256 cols ----
    f16x4 a2[8];
    {
        const char* arow = (const char*)(Bh + (size_t)(n0 + wv * 16 + lr) * 128) + lc * 8;
#pragma unroll
        for (int ks = 0; ks < 8; ++ks)
            a2[ks] = *(const f16x4*)(arow + ks * 32);
    }
    const f16x4* w2f = (const f16x4*)W2p;
    f32x4 acc[16];
#pragma unroll
    for (int nt = 0; nt < 16; ++nt) acc[nt] = (f32x4){0.f, 0.f, 0.f, 0.f};

    f16x4 bcur[16], bnxt[16];
#pragma unroll
    for (int nt = 0; nt < 16; ++nt) bcur[nt] = w2f[(nt * 8 + 0) * 64 + lane];
#pragma unroll
    for (int ks = 0; ks < 8; ++ks) {
        if (ks + 1 < 8) {
#pragma unroll
            for (int nt = 0; nt < 16; ++nt) bnxt[nt] = w2f[(nt * 8 + ks + 1) * 64 + lane];
        }
#pragma unroll
        for (int nt = 0; nt < 16; ++nt)
            acc[nt] = __builtin_amdgcn_mfma_f32_16x16x16f16(a2[ks], bcur[nt], acc[nt], 0, 0, 0);
#pragma unroll
        for (int nt = 0; nt < 16; ++nt) bcur[nt] = bnxt[nt];
    }
    // epilogue: bias+relu -> Ct (swizzled)
#pragma unroll
    for (int nt = 0; nt < 16; ++nt) {
        float bias = b2[nt * 16 + lr];
#pragma unroll
        for (int r = 0; r < 4; ++r) {
            int row = wv * 16 + lc * 4 + r;
            int coff = (nt * 16 + lr) * 2;
            float v = fmaxf(acc[nt][r] + bias, 0.f);
            *(half_t*)(CtB + row * 512 + (coff ^ ((row & 7) << 4))) = (half_t)v;
        }
    }
    __syncthreads();

    // ---- GEMM3: [64x256] @ [256x128], 8 indep acc ----
    f16x4 a3[16];
    {
        int row = wv * 16 + lr;
        const char* rbase = CtB + row * 512;
        int sw = (row & 7) << 4;
#pragma unroll
        for (int ks = 0; ks < 16; ++ks)
            a3[ks] = *(const f16x4*)(rbase + ((ks * 32 + lc * 8) ^ sw));
    }
    const f16x4* w3f = (const f16x4*)W3p;
    f32x4 acc3[8];
#pragma unroll
    for (int nt = 0; nt < 8; ++nt) acc3[nt] = (f32x4){0.f, 0.f, 0.f, 0.f};

    f16x4 ccur[8], cnxt[8];
#pragma unroll
    for (int nt = 0; nt < 8; ++nt) ccur[nt] = w3f[(nt * 16 + 0) * 64 + lane];
#pragma unroll
    for (int ks = 0; ks < 16; ++ks) {
        if (ks + 1 < 16) {
#pragma unroll
            for (int nt = 0; nt < 8; ++nt) cnxt[nt] = w3f[(nt * 16 + ks + 1) * 64 + lane];
        }
#pragma unroll
        for (int nt = 0; nt < 8; ++nt)
            acc3[nt] = __builtin_amdgcn_mfma_f32_16x16x16f16(a3[ks], ccur[nt], acc3[nt], 0, 0, 0);
#pragma unroll
        for (int nt = 0; nt < 8; ++nt) ccur[nt] = cnxt[nt];
    }
#pragma unroll
    for (int nt = 0; nt < 8; ++nt) {
#pragma unroll
        for (int r = 0; r < 4; ++r) {
            int row = n0 + wv * 16 + lc * 4 + r;
            Ah[(size_t)row * 128 + nt * 16 + lr] = (half_t)acc3[nt][r];
        }
    }
}

// mean pool per graph; batch sorted -> binary search segment
__global__ __launch_bounds__(128) void k_pool(const half_t* __restrict__ h,
                                              const int* __restrict__ batch,
                                              float* __restrict__ pooled) {
    int g = blockIdx.x;
    int j = threadIdx.x;
    int lo = 0, hi = NN;
    while (lo < hi) { int mid = (lo + hi) >> 1; if (batch[mid] < g) lo = mid + 1; else hi = mid; }
    int s0 = lo;
    lo = s0; hi = NN;
    while (lo < hi) { int mid = (lo + hi) >> 1; if (batch[mid] < g + 1) lo = mid + 1; else hi = mid; }
    int s1 = lo;
    float acc = 0.f;
    for (int n = s0; n < s1; ++n) acc += (float)h[(size_t)n * 128 + j];
    float c = (float)(s1 - s0);
    if (c < 1.f) c = 1.f;
    pooled[g * 128 + j] = acc / c;
}

__global__ __launch_bounds__(128) void k_mlp(const float* __restrict__ pooled,
                                             const float* __restrict__ Wf1,
                                             const float* __restrict__ bf1,
                                             const float* __restrict__ Wf2,
                                             const float* __restrict__ bf2,
                                             float* __restrict__ out) {
    __shared__ float p[128];
    __shared__ float z[32];
    int g = blockIdx.x;
    int t = threadIdx.x;
    p[t] = pooled[g * 128 + t];
    __syncthreads();
    if (t < 32) {
        float a = bf1[t];
        for (int k = 0; k < 128; ++k) a = fmaf(p[k], Wf1[k * 32 + t], a);
        z[t] = fmaxf(a, 0.f);
    }
    __syncthreads();
    if (t < 2) {
        float a = bf2[t];
        for (int j = 0; j < 32; ++j) a = fmaf(z[j], Wf2[j * 2 + t], a);
        out[g * 2 + t] = a;
    }
}

extern "C" void kernel_launch(void* const* d_in, const int* in_sizes, int n_in,
                              void* d_out, int out_size, void* d_ws, size_t ws_size,
                              hipStream_t stream) {
    const float* x   = (const float*)d_in[0];
    const int*   ei  = (const int*)d_in[1];
    const float* w   = (const float*)d_in[2];
    const int*   bat = (const int*)d_in[3];
    const float* W1  = (const float*)d_in[4];
    const float* b1  = (const float*)d_in[5];
    const float* W2  = (const float*)d_in[6];
    const float* b2  = (const float*)d_in[7];
    const float* W3  = (const float*)d_in[8];
    const float* b3  = (const float*)d_in[9];
    const float* Wf1 = (const float*)d_in[10];
    const float* bf1 = (const float*)d_in[11];
    const float* Wf2 = (const float*)d_in[12];
    const float* bf2 = (const float*)d_in[13];
    float* out = (float*)d_out;

    char* ws = (char*)d_ws;
    size_t o = 0;
    auto alloc = [&](size_t bytes) {
        void* p = ws + o;
        o += (bytes + 255) & ~(size_t)255;
        return p;
    };
    int*    cnt    = (int*)alloc((size_t)NN * 4);
    int*    offs   = (int*)alloc((size_t)(NN + 1) * 4);
    int*    cur    = (int*)alloc((size_t)NN * 4);
    uint2*  pairs  = (uint2*)alloc((size_t)EE * 8);          // 16 MB
    float2* xd     = (float2*)alloc((size_t)NN * 8);         // 1 MB
    half_t* Ah     = (half_t*)alloc((size_t)NN * 128 * 2);   // 32 MB
    half_t* Bh     = (half_t*)alloc((size_t)NN * 128 * 2);   // 32 MB
    half_t* W2p    = (half_t*)alloc((size_t)256 * 128 * 2);
    half_t* W3p    = (half_t*)alloc((size_t)128 * 256 * 2);
    float*  pooled = (float*)alloc((size_t)GG * 128 * 4);

    if (o > ws_size) {
        fprintf(stderr, "[kernel_launch] ws_size=%zu < needed=%zu — aborting launch\n",
                ws_size, o);
        return;
    }

    k_init<<<NN / 256, 256, 0, stream>>>(cnt);
    k_cnt<<<EE / 256, 256, 0, stream>>>(ei, cnt);
    k_scan<<<1, 1024, 0, stream>>>(cnt, offs, cur);
    k_scatter<<<EE / 256, 256, 0, stream>>>(ei, w, cur, pairs);
    k_degdis<<<NN / 256, 256, 0, stream>>>(x, offs, pairs, xd);
    k_w2p<<<128, 256, 0, stream>>>(W2, W2p);
    k_w3p<<<128, 256, 0, stream>>>(W3, W3p);
    k_h1f<<<NN / 4, 256, 0, stream>>>(xd, offs, pairs, W1, b1, Ah);
    k_prop<0><<<NN / 4, 256, 0, stream>>>(Ah, Bh, xd, offs, pairs, nullptr);
    k_gemm23<<<NN / 64, 256, 0, stream>>>(Bh, W2p, b2, W3p, Ah);
    k_prop<1><<<NN / 4, 256, 0, stream>>>(Ah, Bh, xd, offs, pairs, b3);
    k_pool<<<GG, 128, 0, stream>>>(Bh, bat, pooled);
    k_mlp<<<GG, 128, 0, stream>>>(pooled, Wf1, bf1, Wf2, bf2, out);
}